// Round 1
// baseline (57.257 us; speedup 1.0000x reference)
//
#include <hip/hip_runtime.h>

// decoderTriNet: reference collapses analytically.
//   tau = remainder(t_k - n, 128)                          [B,N,K]
//   b_tri[j] = 64.0078125 - j/64 (exact in f32; uniform knot grid)
//   d2 of relu over uniform knots = (1/64) * triangular hat of width 2
//   => phi_hat = (1/64) * (c[m]*(1-f) + c[m+1]*f),  u1 = 64*tau + 4095.5,
//      m = floor(u1), f = u1 - m, contributions only for m in [0,8192).
// All arithmetic in f64: exact replication of an f64 numpy reference
// (tau via fmod is exact for f32 inputs; u1 exact; only final rounding).

#define B_ 16
#define N_ 128
#define K_ 8
#define KNOTS_ 8192

__global__ __launch_bounds__(256) void decoder_tri_kernel(
    const float* __restrict__ t_k_hat,   // [B,K] = [16,8]
    const float* __restrict__ c_tri,     // [8192]
    float* __restrict__ out)             // [B,N,K] = [16,128,8]
{
    int idx = blockIdx.x * 256 + threadIdx.x;   // 0 .. 16383
    int k = idx & (K_ - 1);
    int n = (idx >> 3) & (N_ - 1);
    int b = idx >> 10;

    double t = (double)t_k_hat[b * K_ + k];
    double tau = fmod(t - (double)n, 128.0);
    if (tau < 0.0) tau += 128.0;                 // numpy remainder semantics

    double u1 = tau * 64.0 + 4095.5;             // = 64*(tau + 64.0078125) - 1
    double mf = floor(u1);
    int m = (int)mf;
    double f = u1 - mf;

    double acc = 0.0;
    if (m >= 0 && m < KNOTS_)
        acc += (double)c_tri[m] * (1.0 - f);
    if (m + 1 >= 0 && m + 1 < KNOTS_)
        acc += (double)c_tri[m + 1] * f;

    out[idx] = (float)(acc * (1.0 / 64.0));
}

extern "C" void kernel_launch(void* const* d_in, const int* in_sizes, int n_in,
                              void* d_out, int out_size, void* d_ws, size_t ws_size,
                              hipStream_t stream) {
    const float* t_k  = (const float*)d_in[0];   // [16,8]
    const float* c_tri = (const float*)d_in[1];  // [8192]
    // d_in[2] (b_tri) is deterministic and folded into the closed form.
    float* out = (float*)d_out;                  // [16,128,8] f32

    int total = B_ * N_ * K_;                    // 16384
    decoder_tri_kernel<<<dim3((total + 255) / 256), dim3(256), 0, stream>>>(
        t_k, c_tri, out);
}